// Round 1
// baseline (159.362 us; speedup 1.0000x reference)
//
#include <hip/hip_runtime.h>
#include <math.h>

#define NUM_V 512
#define NUM_F 1024
#define IMG_H 256
#define TAN_T 0.57735026919f      // tan(30 deg)
#define INV_SIGMA 10000.0f        // 1/1e-4
#define LOG_EPS  -13.8155106f     // log(1e-6)

// ---------------------------------------------------------------------------
// Kernel A: camera transform + vertex projection + per-face edge constants.
// One block, 256 threads.  Output: faceData[NUM_F*3] float4s in workspace:
//   w0 = {A0,B0,C0,A1}, w1 = {B1,C1,A2,B2}, w2 = {C2,valid,0,0}
// Edge distance for pixel q: d = A*qy - B*qx - C.
// ---------------------------------------------------------------------------
__global__ __launch_bounds__(256) void setup_kernel(
    const float* __restrict__ verts,   // (NUM_V,3)
    const int*   __restrict__ faces,   // (NUM_F,3)
    const float* __restrict__ cam,     // (3,)
    float4* __restrict__ faceData)     // NUM_F*3 float4s
{
    __shared__ float sx[NUM_V], sy[NUM_V], sz[NUM_V];
    const int tid = threadIdx.x;

    // camera basis (computed redundantly by every thread -- trivial cost)
    const float ex = cam[0], ey = cam[1], ez = cam[2];
    float inv = 1.0f / (sqrtf(ex*ex + ey*ey + ez*ez) + 1e-8f);
    const float zx = -ex*inv, zy = -ey*inv, zz = -ez*inv;
    // x_axis = normalize(cross(up=(0,1,0), z))
    float xxr = 1.0f*zz - 0.0f*zy;
    float xyr = 0.0f*zx - 0.0f*zz;
    float xzr = 0.0f*zy - 1.0f*zx;
    inv = 1.0f / (sqrtf(xxr*xxr + xyr*xyr + xzr*xzr) + 1e-8f);
    const float xx = xxr*inv, xy = xyr*inv, xz = xzr*inv;
    // y_axis = normalize(cross(z, x))
    float yxr = zy*xz - zz*xy;
    float yyr = zz*xx - zx*xz;
    float yzr = zx*xy - zy*xx;
    inv = 1.0f / (sqrtf(yxr*yxr + yyr*yyr + yzr*yzr) + 1e-8f);
    const float yx = yxr*inv, yy = yyr*inv, yz = yzr*inv;

    // project vertices
    for (int v = tid; v < NUM_V; v += 256) {
        float px = verts[3*v+0] - ex;
        float py = verts[3*v+1] - ey;
        float pz = verts[3*v+2] - ez;
        float vx = xx*px + xy*py + xz*pz;
        float vy = yx*px + yy*py + yz*pz;
        float vz = zx*px + zy*py + zz*pz;
        float denom = 1.0f / (vz*TAN_T + 1e-8f);
        sx[v] = vx*denom;
        sy[v] = vy*denom;
        sz[v] = vz;
    }
    __syncthreads();

    // per-face edge constants
    for (int f = tid; f < NUM_F; f += 256) {
        int i0 = faces[3*f+0], i1 = faces[3*f+1], i2 = faces[3*f+2];
        float ax = sx[i0], ay = sy[i0], z0 = sz[i0];
        float bx = sx[i1], by = sy[i1], z1 = sz[i1];
        float cx = sx[i2], cy = sy[i2], z2 = sz[i2];
        float valid = (z0 > 0.001f && z1 > 0.001f && z2 > 0.001f) ? 1.0f : 0.0f;

        float A[3], B[3], C[3];
        const float px_[3] = {ax, bx, cx}, py_[3] = {ay, by, cy};
        const float qx_[3] = {bx, cx, ax}, qy_[3] = {by, cy, ay};
        #pragma unroll
        for (int k = 0; k < 3; ++k) {
            float eex = qx_[k] - px_[k];
            float eey = qy_[k] - py_[k];
            float il = 1.0f / (sqrtf(eex*eex + eey*eey) + 1e-8f);
            A[k] = eex*il;
            B[k] = eey*il;
            C[k] = (eex*py_[k] - eey*px_[k])*il;
        }
        faceData[f*3+0] = make_float4(A[0], B[0], C[0], A[1]);
        faceData[f*3+1] = make_float4(B[1], C[1], A[2], B[2]);
        faceData[f*3+2] = make_float4(C[2], valid, 0.0f, 0.0f);
    }
}

// ---------------------------------------------------------------------------
// Kernel B: per-pixel soft-rasterize loop over faces.
// Grid 256 x 256 threads = 65536 threads, one pixel each.
// ---------------------------------------------------------------------------
static __device__ __forceinline__ float face_term(const float4* __restrict__ sf,
                                                  int f, float qx, float qy)
{
    float4 w0 = sf[f*3+0];
    float4 w1 = sf[f*3+1];
    float4 w2 = sf[f*3+2];
    float d0 = w0.x*qy - w0.y*qx - w0.z;
    float d1 = w0.w*qy - w1.x*qx - w1.y;
    float d2 = w1.z*qy - w1.w*qx - w2.x;
    float dmin = fminf(fminf(d0, d1), d2);
    float dmax = fmaxf(fmaxf(d0, d1), d2);
    float dist = fmaxf(dmin, -dmax);
    float s = dist * fabsf(dist) * INV_SIGMA;
    // log1p(-sigmoid(s)) = -softplus(s), stable form; clip at log(1e-6)
    float e  = __expf(-fabsf(s));
    float sp = fmaxf(s, 0.0f) + __logf(1.0f + e);
    float term = fmaxf(-sp, LOG_EPS);
    return w2.y * term;
}

__global__ __launch_bounds__(256) void render_kernel(
    const float*  __restrict__ image_ref,  // (IMG_H*IMG_H)
    const float4* __restrict__ faceData,   // NUM_F*3
    float* __restrict__ partials)          // one per block
{
    __shared__ float4 sf[NUM_F*3];         // 48 KB
    __shared__ float wsum[4];
    const int tid = threadIdx.x;

    for (int k = tid; k < NUM_F*3; k += 256) sf[k] = faceData[k];
    __syncthreads();

    const int p = blockIdx.x * 256 + tid;
    const int i = p >> 8;         // row
    const int j = p & 255;        // col
    const float qx = (j + 0.5f) * (2.0f / IMG_H) - 1.0f;
    const float qy = 1.0f - (i + 0.5f) * (2.0f / IMG_H);

    float a0 = 0.0f, a1 = 0.0f, a2 = 0.0f, a3 = 0.0f;
    for (int f = 0; f < NUM_F; f += 4) {
        a0 += face_term(sf, f + 0, qx, qy);
        a1 += face_term(sf, f + 1, qx, qy);
        a2 += face_term(sf, f + 2, qx, qy);
        a3 += face_term(sf, f + 3, qx, qy);
    }
    const float accum = (a0 + a1) + (a2 + a3);

    const float alpha = 1.0f - __expf(accum);
    const float diff  = image_ref[p] - alpha;
    float sq = diff * diff;

    // wave64 shuffle reduce, then 4 wave results via LDS
    #pragma unroll
    for (int off = 32; off > 0; off >>= 1) sq += __shfl_down(sq, off, 64);
    if ((tid & 63) == 0) wsum[tid >> 6] = sq;
    __syncthreads();
    if (tid == 0) partials[blockIdx.x] = (wsum[0] + wsum[1]) + (wsum[2] + wsum[3]);
}

// ---------------------------------------------------------------------------
// Kernel C: final reduction + distance penalty
// ---------------------------------------------------------------------------
__global__ __launch_bounds__(256) void finalize_kernel(
    const float* __restrict__ partials,
    const float* __restrict__ cam,
    float* __restrict__ out)
{
    __shared__ float red[256];
    const int tid = threadIdx.x;
    red[tid] = partials[tid];
    __syncthreads();
    for (int s = 128; s > 0; s >>= 1) {
        if (tid < s) red[tid] += red[tid + s];
        __syncthreads();
    }
    if (tid == 0) {
        float ex = cam[0], ey = cam[1], ez = cam[2];
        float dist = sqrtf(ex*ex + ey*ey + ez*ez);
        float pen = fmaxf(6.0f - dist, 0.0f);
        out[0] = red[0] * (1.0f + pen);
    }
}

extern "C" void kernel_launch(void* const* d_in, const int* in_sizes, int n_in,
                              void* d_out, int out_size, void* d_ws, size_t ws_size,
                              hipStream_t stream)
{
    const float* verts     = (const float*)d_in[0];  // (1,512,3)
    const int*   faces     = (const int*)  d_in[1];  // (1,1024,3)
    const float* image_ref = (const float*)d_in[2];  // (256,256)
    const float* cam       = (const float*)d_in[3];  // (3,)

    float*  ws       = (float*)d_ws;
    float4* faceData = (float4*)ws;                  // NUM_F*3 float4s = 48 KB
    float*  partials = ws + 12 * NUM_F;              // 256 floats
    float*  out      = (float*)d_out;

    setup_kernel   <<<1,   256, 0, stream>>>(verts, faces, cam, faceData);
    render_kernel  <<<256, 256, 0, stream>>>(image_ref, faceData, partials);
    finalize_kernel<<<1,   256, 0, stream>>>(partials, cam, out);
}

// Round 2
// 114.445 us; speedup vs baseline: 1.3925x; 1.3925x over previous
//
#include <hip/hip_runtime.h>
#include <math.h>

#define NUM_V 512
#define NUM_F 1024
#define IMG_H 256
#define NPIX (IMG_H*IMG_H)
#define NCHUNK 4
#define FPC (NUM_F/NCHUNK)        // 256 faces per chunk
#define TAN_T 0.57735026919f      // tan(30 deg)
#define INV_SIGMA 10000.0f        // 1/1e-4
#define LOG_EPS  -13.8155106f     // log(1e-6)
#define DCULL    -0.0372f         // dist below this => |term| < 1e-6, safe to skip

// ---------------------------------------------------------------------------
// Render kernel. Grid = 256 pixel-tiles * NCHUNK face-chunks = 1024 blocks.
// Each block: (a) redundantly projects all 512 verts + computes edge constants
// for its 256-face chunk into LDS (cheap: ~70 instr/thread), (b) loops its
// chunk over the block's 16x16 pixel tile, (c) writes per-pixel partial
// log-sum to ws. Waves cover 8x8 sub-tiles so the dist-based transcendental
// skip is wave-coherent.
// ---------------------------------------------------------------------------
__global__ __launch_bounds__(256, 4) void render_kernel(
    const float* __restrict__ verts,   // (NUM_V,3)
    const int*   __restrict__ faces,   // (NUM_F,3)
    const float* __restrict__ cam,     // (3,)
    float* __restrict__ partials)      // NCHUNK * NPIX
{
    __shared__ float sx[NUM_V], sy[NUM_V], sz[NUM_V];   // 6 KB
    __shared__ float4 sf[FPC*3];                        // 12 KB
    const int tid = threadIdx.x;
    const int chunk = blockIdx.x >> 8;        // 0..3
    const int tile  = blockIdx.x & 255;       // 0..255

    // ---- camera basis (every thread, trivial) ----
    const float ex = cam[0], ey = cam[1], ez = cam[2];
    float inv = 1.0f / (sqrtf(ex*ex + ey*ey + ez*ez) + 1e-8f);
    const float zx = -ex*inv, zy = -ey*inv, zz = -ez*inv;
    float xxr = zz, xyr = 0.0f, xzr = -zx;    // cross((0,1,0), z)
    inv = 1.0f / (sqrtf(xxr*xxr + xyr*xyr + xzr*xzr) + 1e-8f);
    const float xx = xxr*inv, xy = xyr*inv, xz = xzr*inv;
    float yxr = zy*xz - zz*xy;
    float yyr = zz*xx - zx*xz;
    float yzr = zx*xy - zy*xx;
    inv = 1.0f / (sqrtf(yxr*yxr + yyr*yyr + yzr*yzr) + 1e-8f);
    const float yx = yxr*inv, yy = yyr*inv, yz = yzr*inv;

    // ---- project vertices (2 per thread) ----
    for (int v = tid; v < NUM_V; v += 256) {
        float px = verts[3*v+0] - ex;
        float py = verts[3*v+1] - ey;
        float pz = verts[3*v+2] - ez;
        float vx = xx*px + xy*py + xz*pz;
        float vy = yx*px + yy*py + yz*pz;
        float vz = zx*px + zy*py + zz*pz;
        float denom = 1.0f / (vz*TAN_T + 1e-8f);
        sx[v] = vx*denom;
        sy[v] = vy*denom;
        sz[v] = vz;
    }
    __syncthreads();

    // ---- edge constants for this chunk (1 face per thread) ----
    {
        const int f = chunk*FPC + tid;
        int i0 = faces[3*f+0], i1 = faces[3*f+1], i2 = faces[3*f+2];
        float ax = sx[i0], ay = sy[i0], z0 = sz[i0];
        float bx = sx[i1], by = sy[i1], z1 = sz[i1];
        float cx = sx[i2], cy = sy[i2], z2 = sz[i2];
        bool valid = (z0 > 0.001f && z1 > 0.001f && z2 > 0.001f);

        float A[3], B[3], C[3];
        const float px_[3] = {ax, bx, cx}, py_[3] = {ay, by, cy};
        const float qx_[3] = {bx, cx, ax}, qy_[3] = {by, cy, ay};
        #pragma unroll
        for (int k = 0; k < 3; ++k) {
            float eex = qx_[k] - px_[k];
            float eey = qy_[k] - py_[k];
            float il = 1.0f / (sqrtf(eex*eex + eey*eey) + 1e-8f);
            A[k] = eex*il;
            B[k] = eey*il;
            C[k] = (eex*py_[k] - eey*px_[k])*il;
        }
        if (!valid) { C[0] = 1e30f; C[1] = -1e30f; }  // forces dist=-1e30 -> term 0, always culled
        sf[tid*3+0] = make_float4(A[0], B[0], C[0], A[1]);
        sf[tid*3+1] = make_float4(B[1], C[1], A[2], B[2]);
        sf[tid*3+2] = make_float4(C[2], 0.0f, 0.0f, 0.0f);
    }
    __syncthreads();

    // ---- pixel for this thread: wave = 8x8 sub-tile, block = 16x16 tile ----
    const int w  = tid >> 6;                  // wave in block (2x2 sub-tiles)
    const int l  = tid & 63;
    const int j  = (tile & 15)*16 + (w & 1)*8 + (l & 7);        // col
    const int i  = (tile >> 4)*16 + (w >> 1)*8 + (l >> 3);      // row
    const int p  = i*IMG_H + j;
    const float qx = (j + 0.5f) * (2.0f / IMG_H) - 1.0f;
    const float qy = 1.0f - (i + 0.5f) * (2.0f / IMG_H);

    float acc = 0.0f;
    #pragma unroll 1
    for (int lf = 0; lf < FPC; lf += 4) {
        float dist4[4];
        #pragma unroll
        for (int u = 0; u < 4; ++u) {
            float4 w0 = sf[(lf+u)*3+0];
            float4 w1 = sf[(lf+u)*3+1];
            float4 w2 = sf[(lf+u)*3+2];
            float d0 = fmaf(w0.x, qy, -fmaf(w0.y, qx, w0.z));
            float d1 = fmaf(w0.w, qy, -fmaf(w1.x, qx, w1.y));
            float d2 = fmaf(w1.z, qy, -fmaf(w1.w, qx, w2.x));
            float dmin = fminf(fminf(d0, d1), d2);
            float dmax = fmaxf(fmaxf(d0, d1), d2);
            dist4[u] = fmaxf(dmin, -dmax);
        }
        float gm = fmaxf(fmaxf(dist4[0], dist4[1]), fmaxf(dist4[2], dist4[3]));
        if (__any(gm > DCULL)) {
            #pragma unroll
            for (int u = 0; u < 4; ++u) {
                float dist = dist4[u];
                float s  = (dist * INV_SIGMA) * fabsf(dist);
                // -softplus(s), stable; exp2/log2 map to single v_exp/v_log
                float e2 = __builtin_exp2f(-fabsf(s) * 1.44269504f);
                float lg = __builtin_log2f(1.0f + e2);
                float sp = fmaf(lg, 0.69314718f, fmaxf(s, 0.0f));
                acc += fmaxf(-sp, LOG_EPS);
            }
        }
    }
    partials[chunk*NPIX + p] = acc;
}

// ---------------------------------------------------------------------------
// Finalize: sum chunk partials per pixel, alpha, squared error, global reduce.
// ---------------------------------------------------------------------------
__global__ __launch_bounds__(256) void finalize_kernel(
    const float* __restrict__ image_ref,
    const float* __restrict__ partials,
    const float* __restrict__ cam,
    float* __restrict__ out)
{
    __shared__ float wsum[4];
    const int tid = threadIdx.x;
    const int p = blockIdx.x*256 + tid;

    float lsum = partials[p] + partials[NPIX + p]
               + partials[2*NPIX + p] + partials[3*NPIX + p];
    float alpha = 1.0f - __expf(lsum);
    float diff  = image_ref[p] - alpha;
    float sq = diff * diff;

    #pragma unroll
    for (int off = 32; off > 0; off >>= 1) sq += __shfl_down(sq, off, 64);
    if ((tid & 63) == 0) wsum[tid >> 6] = sq;
    __syncthreads();
    if (tid == 0) {
        float ex = cam[0], ey = cam[1], ez = cam[2];
        float dist = sqrtf(ex*ex + ey*ey + ez*ez);
        float pen = fmaxf(6.0f - dist, 0.0f);
        float bs = (wsum[0] + wsum[1]) + (wsum[2] + wsum[3]);
        atomicAdd(out, bs * (1.0f + pen));
    }
}

extern "C" void kernel_launch(void* const* d_in, const int* in_sizes, int n_in,
                              void* d_out, int out_size, void* d_ws, size_t ws_size,
                              hipStream_t stream)
{
    const float* verts     = (const float*)d_in[0];  // (1,512,3)
    const int*   faces     = (const int*)  d_in[1];  // (1,1024,3)
    const float* image_ref = (const float*)d_in[2];  // (256,256)
    const float* cam       = (const float*)d_in[3];  // (3,)

    float* partials = (float*)d_ws;                  // NCHUNK*NPIX floats = 1 MB
    float* out      = (float*)d_out;

    hipMemsetAsync(out, 0, sizeof(float), stream);
    render_kernel  <<<256*NCHUNK, 256, 0, stream>>>(verts, faces, cam, partials);
    finalize_kernel<<<NPIX/256,   256, 0, stream>>>(image_ref, partials, cam, out);
}

// Round 3
// 84.497 us; speedup vs baseline: 1.8860x; 1.3544x over previous
//
#include <hip/hip_runtime.h>
#include <math.h>

#define NUM_V 512
#define NUM_F 1024
#define IMG_H 256
#define NPIX (IMG_H*IMG_H)
#define NCHUNK 8
#define FPC (NUM_F/NCHUNK)        // 128 faces per chunk
#define TAN_T 0.57735026919f      // tan(30 deg)
#define INV_SIGMA 10000.0f        // 1/1e-4
#define LOG_EPS  -13.8155106f     // log(1e-6)
#define DCULL    -0.0372f         // dist <= DCULL  =>  |log1p(-sigmoid)| < 1e-6

// ---------------------------------------------------------------------------
// Render kernel. Grid = 256 pixel-tiles (16x16 px) x NCHUNK face-chunks.
// chunk = fast-varying blockIdx bits => one tile's chunks round-robin across
// XCDs for load balance on the few "heavy" tiles.
// Per block:
//   prologue: project 512 verts (redundant, ~cheap), build edge constants for
//             the chunk's 128 faces, CULL vs tile rect (exact affine corner
//             bound), compact survivors into LDS.
//   main:     only if survivors > 0 -- loop survivor groups of 4 over the
//             block's 16x16 pixels (wave = 8x8 sub-tile for coherent
//             transcendental skip), atomicAdd per-pixel log-sum partials.
// ~250/256 tiles exit with 0 survivors after the prologue.
// ---------------------------------------------------------------------------
__global__ __launch_bounds__(256, 8) void render_kernel(
    const float* __restrict__ verts,   // (NUM_V,3)
    const int*   __restrict__ faces,   // (NUM_F,3)
    const float* __restrict__ cam,     // (3,)
    float* __restrict__ partials)      // NPIX floats, pre-zeroed
{
    __shared__ float sx[NUM_V], sy[NUM_V], sz[NUM_V];   // 6 KB
    __shared__ float4 sf[(FPC+4)*3];                    // ~6.2 KB survivors
    __shared__ int scnt;
    const int tid   = threadIdx.x;
    const int chunk = blockIdx.x & (NCHUNK-1);
    const int tile  = blockIdx.x / NCHUNK;

    if (tid == 0) scnt = 0;

    // ---- camera basis (every thread, trivial) ----
    const float ex = cam[0], ey = cam[1], ez = cam[2];
    float inv = 1.0f / (sqrtf(ex*ex + ey*ey + ez*ez) + 1e-8f);
    const float zx = -ex*inv, zy = -ey*inv, zz = -ez*inv;
    float xxr = zz, xyr = 0.0f, xzr = -zx;    // cross((0,1,0), z)
    inv = 1.0f / (sqrtf(xxr*xxr + xyr*xyr + xzr*xzr) + 1e-8f);
    const float xx = xxr*inv, xy = xyr*inv, xz = xzr*inv;
    float yxr = zy*xz - zz*xy;
    float yyr = zz*xx - zx*xz;
    float yzr = zx*xy - zy*xx;
    inv = 1.0f / (sqrtf(yxr*yxr + yyr*yyr + yzr*yzr) + 1e-8f);
    const float yx = yxr*inv, yy = yyr*inv, yz = yzr*inv;

    // ---- project vertices (2 per thread) ----
    for (int v = tid; v < NUM_V; v += 256) {
        float px = verts[3*v+0] - ex;
        float py = verts[3*v+1] - ey;
        float pz = verts[3*v+2] - ez;
        float vx = xx*px + xy*py + xz*pz;
        float vy = yx*px + yy*py + yz*pz;
        float vz = zx*px + zy*py + zz*pz;
        float denom = 1.0f / (vz*TAN_T + 1e-8f);
        sx[v] = vx*denom;
        sy[v] = vy*denom;
        sz[v] = vz;
    }
    __syncthreads();   // covers scnt init too

    // ---- tile rect (pixel-center corners; d is affine so corners bound it) ----
    const int j0 = (tile & 15) * 16;
    const int i0 = (tile >> 4) * 16;
    const float xL = (j0 + 0.5f )*(2.0f/IMG_H) - 1.0f;
    const float xR = (j0 + 15.5f)*(2.0f/IMG_H) - 1.0f;
    const float yT = 1.0f - (i0 + 0.5f )*(2.0f/IMG_H);
    const float yB = 1.0f - (i0 + 15.5f)*(2.0f/IMG_H);

    // ---- cull + compact this chunk's faces ----
    if (tid < FPC) {
        const int f = chunk*FPC + tid;
        int i0f = faces[3*f+0], i1f = faces[3*f+1], i2f = faces[3*f+2];
        float ax = sx[i0f], ay = sy[i0f], z0 = sz[i0f];
        float bx = sx[i1f], by = sy[i1f], z1 = sz[i1f];
        float cx = sx[i2f], cy = sy[i2f], z2 = sz[i2f];
        bool keep = (z0 > 0.001f && z1 > 0.001f && z2 > 0.001f);

        float A[3], B[3], C[3];
        const float px_[3] = {ax, bx, cx}, py_[3] = {ay, by, cy};
        const float qx_[3] = {bx, cx, ax}, qy_[3] = {by, cy, ay};
        #pragma unroll
        for (int k = 0; k < 3; ++k) {
            float eex = qx_[k] - px_[k];
            float eey = qy_[k] - py_[k];
            float il = 1.0f / (sqrtf(eex*eex + eey*eey) + 1e-8f);
            A[k] = eex*il;
            B[k] = eey*il;
            C[k] = (eex*py_[k] - eey*px_[k])*il;
        }

        if (keep) {
            // skip iff  (min_k max_q d_k <= DCULL) && (max_k min_q d_k >= -DCULL)
            // => forall q in tile: dist(q) = max(dmin,-dmax) <= DCULL
            float minmx = 3.0e38f, maxmn = -3.0e38f;
            #pragma unroll
            for (int k = 0; k < 3; ++k) {
                float dTL = A[k]*yT - B[k]*xL - C[k];
                float dTR = A[k]*yT - B[k]*xR - C[k];
                float dBL = A[k]*yB - B[k]*xL - C[k];
                float dBR = A[k]*yB - B[k]*xR - C[k];
                float mx = fmaxf(fmaxf(dTL, dTR), fmaxf(dBL, dBR));
                float mn = fminf(fminf(dTL, dTR), fminf(dBL, dBR));
                minmx = fminf(minmx, mx);
                maxmn = fmaxf(maxmn, mn);
            }
            keep = !((minmx <= DCULL) && (maxmn >= -DCULL));
        }
        if (keep) {
            int s = atomicAdd(&scnt, 1);
            sf[s*3+0] = make_float4(A[0], B[0], C[0], A[1]);
            sf[s*3+1] = make_float4(B[1], C[1], A[2], B[2]);
            sf[s*3+2] = make_float4(C[2], 0.0f, 0.0f, 0.0f);
        }
    }
    __syncthreads();

    const int n = scnt;
    if (n == 0) return;   // ~98% of blocks exit here

    // ---- pixel for this thread: wave = 8x8 sub-tile ----
    const int w = tid >> 6, l = tid & 63;
    const int j = j0 + (w & 1)*8 + (l & 7);
    const int i = i0 + (w >> 1)*8 + (l >> 3);
    const int p = i*IMG_H + j;
    const float qx = (j + 0.5f)*(2.0f/IMG_H) - 1.0f;
    const float qy = 1.0f - (i + 0.5f)*(2.0f/IMG_H);

    float acc = 0.0f;
    for (int g = 0; g < n; g += 4) {
        float dist4[4];
        #pragma unroll
        for (int u = 0; u < 4; ++u) {
            float4 w0 = sf[(g+u)*3+0];
            float4 w1 = sf[(g+u)*3+1];
            float4 w2 = sf[(g+u)*3+2];
            float d0 = fmaf(w0.x, qy, -fmaf(w0.y, qx, w0.z));
            float d1 = fmaf(w0.w, qy, -fmaf(w1.x, qx, w1.y));
            float d2 = fmaf(w1.z, qy, -fmaf(w1.w, qx, w2.x));
            float dmin = fminf(fminf(d0, d1), d2);
            float dmax = fmaxf(fmaxf(d0, d1), d2);
            float dd = fmaxf(dmin, -dmax);
            dist4[u] = (g + u < n) ? dd : -1e30f;   // tail groups culled
        }
        float gm = fmaxf(fmaxf(dist4[0], dist4[1]), fmaxf(dist4[2], dist4[3]));
        if (__any(gm > DCULL)) {
            #pragma unroll
            for (int u = 0; u < 4; ++u) {
                float dist = dist4[u];
                float s  = (dist * INV_SIGMA) * fabsf(dist);
                float e2 = __builtin_exp2f(-fabsf(s) * 1.44269504f);
                float lg = __builtin_log2f(1.0f + e2);
                float sp = fmaf(lg, 0.69314718f, fmaxf(s, 0.0f));
                acc += fmaxf(-sp, LOG_EPS);
            }
        }
    }
    atomicAdd(&partials[p], acc);
}

// ---------------------------------------------------------------------------
// Finalize: alpha, squared error, global reduce, distance penalty.
// ---------------------------------------------------------------------------
__global__ __launch_bounds__(256) void finalize_kernel(
    const float* __restrict__ image_ref,
    const float* __restrict__ partials,
    const float* __restrict__ cam,
    float* __restrict__ out)           // pre-zeroed
{
    __shared__ float wsum[4];
    const int tid = threadIdx.x;
    const int p = blockIdx.x*256 + tid;

    float alpha = 1.0f - __expf(partials[p]);
    float diff  = image_ref[p] - alpha;
    float sq = diff * diff;

    #pragma unroll
    for (int off = 32; off > 0; off >>= 1) sq += __shfl_down(sq, off, 64);
    if ((tid & 63) == 0) wsum[tid >> 6] = sq;
    __syncthreads();
    if (tid == 0) {
        float ex = cam[0], ey = cam[1], ez = cam[2];
        float dist = sqrtf(ex*ex + ey*ey + ez*ez);
        float pen = fmaxf(6.0f - dist, 0.0f);
        float bs = (wsum[0] + wsum[1]) + (wsum[2] + wsum[3]);
        atomicAdd(out, bs * (1.0f + pen));
    }
}

extern "C" void kernel_launch(void* const* d_in, const int* in_sizes, int n_in,
                              void* d_out, int out_size, void* d_ws, size_t ws_size,
                              hipStream_t stream)
{
    const float* verts     = (const float*)d_in[0];  // (1,512,3)
    const int*   faces     = (const int*)  d_in[1];  // (1,1024,3)
    const float* image_ref = (const float*)d_in[2];  // (256,256)
    const float* cam       = (const float*)d_in[3];  // (3,)

    float* partials = (float*)d_ws;                  // NPIX floats = 256 KB
    float* out      = (float*)d_out;

    hipMemsetAsync(partials, 0, NPIX*sizeof(float), stream);
    hipMemsetAsync(out, 0, sizeof(float), stream);
    render_kernel  <<<256*NCHUNK, 256, 0, stream>>>(verts, faces, cam, partials);
    finalize_kernel<<<NPIX/256,   256, 0, stream>>>(image_ref, partials, cam, out);
}

// Round 4
// 81.101 us; speedup vs baseline: 1.9650x; 1.0419x over previous
//
#include <hip/hip_runtime.h>
#include <math.h>

#define NUM_V 512
#define NUM_F 1024
#define IMG_H 256
#define NPIX (IMG_H*IMG_H)
#define NCHUNK 8
#define FPC (NUM_F/NCHUNK)        // 128 faces per chunk
#define TAN_T 0.57735026919f      // tan(30 deg)
#define INV_SIGMA 10000.0f        // 1/1e-4
#define LOG_EPS  -13.8155106f     // log(1e-6)
#define DCULL    -0.0372f         // dist <= DCULL  =>  |log1p(-sigmoid)| < 1e-6

// ---------------------------------------------------------------------------
// Render kernel. Grid = 256 pixel-tiles (16x16 px) x NCHUNK face-chunks.
// chunk = fast-varying blockIdx bits (spreads a heavy tile's chunks across
// XCDs). Per block:
//   prologue: project 512 verts, build edge constants for the chunk's 128
//             faces, cull vs tile rect (exact affine corner bound), compact
//             survivors into LDS, pad survivor count to a multiple of 4 with
//             zero-contribution sentinels.
//   main:     loop survivor groups of 4 over the 16x16 pixel tile (wave =
//             8x8 sub-tile for coherent transcendental skip).
//   store:    slice[chunk][p] = acc  (disjoint slices -> plain store, no
//             zero-init of workspace needed despite 0xAA poison).
// Block 0 also zeroes out[0] (finalize, a later dispatch, atomicAdds into it).
// ---------------------------------------------------------------------------
__global__ __launch_bounds__(256, 8) void render_kernel(
    const float* __restrict__ verts,   // (NUM_V,3)
    const int*   __restrict__ faces,   // (NUM_F,3)
    const float* __restrict__ cam,     // (3,)
    float* __restrict__ slices,        // NCHUNK * NPIX floats (fully rewritten)
    float* __restrict__ out)           // zeroed here, used by finalize
{
    __shared__ float sx[NUM_V], sy[NUM_V], sz[NUM_V];   // 6 KB
    __shared__ float4 sf[(FPC+4)*3];                    // ~6.2 KB survivors
    __shared__ int scnt;
    const int tid   = threadIdx.x;
    const int chunk = blockIdx.x & (NCHUNK-1);
    const int tile  = blockIdx.x / NCHUNK;

    if (blockIdx.x == 0 && tid == 0) out[0] = 0.0f;
    if (tid == 0) scnt = 0;

    // ---- camera basis (every thread, trivial) ----
    const float ex = cam[0], ey = cam[1], ez = cam[2];
    float inv = 1.0f / (sqrtf(ex*ex + ey*ey + ez*ez) + 1e-8f);
    const float zx = -ex*inv, zy = -ey*inv, zz = -ez*inv;
    float xxr = zz, xyr = 0.0f, xzr = -zx;    // cross((0,1,0), z)
    inv = 1.0f / (sqrtf(xxr*xxr + xyr*xyr + xzr*xzr) + 1e-8f);
    const float xx = xxr*inv, xy = xyr*inv, xz = xzr*inv;
    float yxr = zy*xz - zz*xy;
    float yyr = zz*xx - zx*xz;
    float yzr = zx*xy - zy*xx;
    inv = 1.0f / (sqrtf(yxr*yxr + yyr*yyr + yzr*yzr) + 1e-8f);
    const float yx = yxr*inv, yy = yyr*inv, yz = yzr*inv;

    // ---- project vertices (2 per thread) ----
    for (int v = tid; v < NUM_V; v += 256) {
        float px = verts[3*v+0] - ex;
        float py = verts[3*v+1] - ey;
        float pz = verts[3*v+2] - ez;
        float vx = xx*px + xy*py + xz*pz;
        float vy = yx*px + yy*py + yz*pz;
        float vz = zx*px + zy*py + zz*pz;
        float denom = 1.0f / (vz*TAN_T + 1e-8f);
        sx[v] = vx*denom;
        sy[v] = vy*denom;
        sz[v] = vz;
    }
    __syncthreads();   // covers scnt init too

    // ---- tile rect (pixel-center corners; d affine -> corners bound it) ----
    const int j0 = (tile & 15) * 16;
    const int i0 = (tile >> 4) * 16;
    const float xL = (j0 + 0.5f )*(2.0f/IMG_H) - 1.0f;
    const float xR = (j0 + 15.5f)*(2.0f/IMG_H) - 1.0f;
    const float yT = 1.0f - (i0 + 0.5f )*(2.0f/IMG_H);
    const float yB = 1.0f - (i0 + 15.5f)*(2.0f/IMG_H);

    // ---- cull + compact this chunk's faces ----
    if (tid < FPC) {
        const int f = chunk*FPC + tid;
        int i0f = faces[3*f+0], i1f = faces[3*f+1], i2f = faces[3*f+2];
        float ax = sx[i0f], ay = sy[i0f], z0 = sz[i0f];
        float bx = sx[i1f], by = sy[i1f], z1 = sz[i1f];
        float cx = sx[i2f], cy = sy[i2f], z2 = sz[i2f];
        bool keep = (z0 > 0.001f && z1 > 0.001f && z2 > 0.001f);

        float A[3], B[3], C[3];
        const float px_[3] = {ax, bx, cx}, py_[3] = {ay, by, cy};
        const float qx_[3] = {bx, cx, ax}, qy_[3] = {by, cy, ay};
        #pragma unroll
        for (int k = 0; k < 3; ++k) {
            float eex = qx_[k] - px_[k];
            float eey = qy_[k] - py_[k];
            float il = 1.0f / (sqrtf(eex*eex + eey*eey) + 1e-8f);
            A[k] = eex*il;
            B[k] = eey*il;
            C[k] = (eex*py_[k] - eey*px_[k])*il;
        }

        if (keep) {
            // skip iff (min_k max_q d_k <= DCULL) && (max_k min_q d_k >= -DCULL)
            float minmx = 3.0e38f, maxmn = -3.0e38f;
            #pragma unroll
            for (int k = 0; k < 3; ++k) {
                float dTL = A[k]*yT - B[k]*xL - C[k];
                float dTR = A[k]*yT - B[k]*xR - C[k];
                float dBL = A[k]*yB - B[k]*xL - C[k];
                float dBR = A[k]*yB - B[k]*xR - C[k];
                float mx = fmaxf(fmaxf(dTL, dTR), fmaxf(dBL, dBR));
                float mn = fminf(fminf(dTL, dTR), fminf(dBL, dBR));
                minmx = fminf(minmx, mx);
                maxmn = fmaxf(maxmn, mn);
            }
            keep = !((minmx <= DCULL) && (maxmn >= -DCULL));
        }
        if (keep) {
            int s = atomicAdd(&scnt, 1);
            sf[s*3+0] = make_float4(A[0], B[0], C[0], A[1]);
            sf[s*3+1] = make_float4(B[1], C[1], A[2], B[2]);
            sf[s*3+2] = make_float4(C[2], 0.0f, 0.0f, 0.0f);
        }
    }
    __syncthreads();

    int n = scnt;
    // pad to multiple of 4 with sentinels: dist=-1e30 -> term exactly 0
    const int npad = (4 - (n & 3)) & 3;
    if (tid < npad) {
        const int s = n + tid;
        sf[s*3+0] = make_float4(0.0f, 0.0f, 1e30f, 0.0f);
        sf[s*3+1] = make_float4(0.0f, -1e30f, 0.0f, 0.0f);
        sf[s*3+2] = make_float4(0.0f, 0.0f, 0.0f, 0.0f);
    }
    __syncthreads();
    n = (n + 3) & ~3;

    // ---- pixel for this thread: wave = 8x8 sub-tile ----
    const int w = tid >> 6, l = tid & 63;
    const int j = j0 + (w & 1)*8 + (l & 7);
    const int i = i0 + (w >> 1)*8 + (l >> 3);
    const int p = i*IMG_H + j;
    const float qx = (j + 0.5f)*(2.0f/IMG_H) - 1.0f;
    const float qy = 1.0f - (i + 0.5f)*(2.0f/IMG_H);

    float acc = 0.0f;
    for (int g = 0; g < n; g += 4) {
        float dist4[4];
        #pragma unroll
        for (int u = 0; u < 4; ++u) {
            float4 w0 = sf[(g+u)*3+0];
            float4 w1 = sf[(g+u)*3+1];
            float4 w2 = sf[(g+u)*3+2];
            float d0 = fmaf(w0.x, qy, -fmaf(w0.y, qx, w0.z));
            float d1 = fmaf(w0.w, qy, -fmaf(w1.x, qx, w1.y));
            float d2 = fmaf(w1.z, qy, -fmaf(w1.w, qx, w2.x));
            float dmin = fminf(fminf(d0, d1), d2);
            float dmax = fmaxf(fmaxf(d0, d1), d2);
            dist4[u] = fmaxf(dmin, -dmax);
        }
        float gm = fmaxf(fmaxf(dist4[0], dist4[1]), fmaxf(dist4[2], dist4[3]));
        if (__any(gm > DCULL)) {
            #pragma unroll
            for (int u = 0; u < 4; ++u) {
                float dist = dist4[u];
                float s  = (dist * INV_SIGMA) * fabsf(dist);
                float e2 = __builtin_exp2f(-fabsf(s) * 1.44269504f);
                float lg = __builtin_log2f(1.0f + e2);
                float sp = fmaf(lg, 0.69314718f, fmaxf(s, 0.0f));
                acc += fmaxf(-sp, LOG_EPS);
            }
        }
    }
    slices[chunk*NPIX + p] = acc;   // disjoint per chunk -> plain store
}

// ---------------------------------------------------------------------------
// Finalize: sum chunk slices per pixel, alpha, squared error, global reduce.
// out[0] was zeroed by render (previous dispatch in stream order).
// ---------------------------------------------------------------------------
__global__ __launch_bounds__(256) void finalize_kernel(
    const float* __restrict__ image_ref,
    const float* __restrict__ slices,
    const float* __restrict__ cam,
    float* __restrict__ out)
{
    __shared__ float wsum[4];
    const int tid = threadIdx.x;
    const int p = blockIdx.x*256 + tid;

    float lsum = 0.0f;
    #pragma unroll
    for (int c = 0; c < NCHUNK; ++c) lsum += slices[c*NPIX + p];
    float alpha = 1.0f - __expf(lsum);
    float diff  = image_ref[p] - alpha;
    float sq = diff * diff;

    #pragma unroll
    for (int off = 32; off > 0; off >>= 1) sq += __shfl_down(sq, off, 64);
    if ((tid & 63) == 0) wsum[tid >> 6] = sq;
    __syncthreads();
    if (tid == 0) {
        float ex = cam[0], ey = cam[1], ez = cam[2];
        float dist = sqrtf(ex*ex + ey*ey + ez*ez);
        float pen = fmaxf(6.0f - dist, 0.0f);
        float bs = (wsum[0] + wsum[1]) + (wsum[2] + wsum[3]);
        atomicAdd(out, bs * (1.0f + pen));
    }
}

extern "C" void kernel_launch(void* const* d_in, const int* in_sizes, int n_in,
                              void* d_out, int out_size, void* d_ws, size_t ws_size,
                              hipStream_t stream)
{
    const float* verts     = (const float*)d_in[0];  // (1,512,3)
    const int*   faces     = (const int*)  d_in[1];  // (1,1024,3)
    const float* image_ref = (const float*)d_in[2];  // (256,256)
    const float* cam       = (const float*)d_in[3];  // (3,)

    float* slices = (float*)d_ws;                    // NCHUNK*NPIX floats = 2 MB
    float* out    = (float*)d_out;

    render_kernel  <<<256*NCHUNK, 256, 0, stream>>>(verts, faces, cam, slices, out);
    finalize_kernel<<<NPIX/256,   256, 0, stream>>>(image_ref, slices, cam, out);
}

// Round 5
// 79.471 us; speedup vs baseline: 2.0053x; 1.0205x over previous
//
#include <hip/hip_runtime.h>
#include <math.h>

#define NUM_V 512
#define NUM_F 1024
#define IMG_H 256
#define NPIX (IMG_H*IMG_H)
#define NCHUNK 16
#define FPC (NUM_F/NCHUNK)        // 64 faces per chunk
#define TAN_T 0.57735026919f      // tan(30 deg)
#define LOG_EPS  -13.8155106f     // log(1e-6)
// Edge constants are pre-scaled by 100 = sqrt(1/SIGMA), so s = d'*|d'| directly.
#define DCULL_S  -3.72f           // scaled dist <= -3.72  =>  |term| < 1e-6

// ---------------------------------------------------------------------------
// Render. Grid = 256 pixel-tiles (16x16 px) x NCHUNK face-chunks, chunk in
// the fast-varying blockIdx bits. Per block:
//   prologue: project 512 verts, build 100x-scaled edge constants for the
//             chunk's 64 faces, cull vs tile rect (exact affine corner
//             bound), compact survivors to LDS (packed 9 floats/face).
//   n==0 (the vast majority): write cnt=0, exit. Slice left poisoned --
//             finalize never reads slices with cnt==0.
//   n>0:      pad to multiple of 4 with zero-contribution sentinels, loop
//             groups of 4 over the 16x16 tile (wave = 8x8 sub-tile for
//             coherent transcendental skip), store 256-float slice.
// Block 0 zeroes out[0] (finalize atomicAdds into it; stream-ordered).
// ---------------------------------------------------------------------------
__global__ __launch_bounds__(256, 8) void render_kernel(
    const float* __restrict__ verts,   // (NUM_V,3)
    const int*   __restrict__ faces,   // (NUM_F,3)
    const float* __restrict__ cam,     // (3,)
    float* __restrict__ slices,        // 256*NCHUNK*256 floats (sparse-written)
    int*   __restrict__ cnt,           // 256*NCHUNK ints (always written)
    float* __restrict__ out)
{
    __shared__ float sx[NUM_V], sy[NUM_V], sz[NUM_V];   // 6 KB
    __shared__ float4 sfA[FPC+4], sfB[FPC+4];           // 2.1 KB
    __shared__ float  sfC[FPC+4];
    __shared__ int scnt;
    const int tid   = threadIdx.x;
    const int chunk = blockIdx.x & (NCHUNK-1);
    const int tile  = blockIdx.x / NCHUNK;

    if (blockIdx.x == 0 && tid == 0) out[0] = 0.0f;
    if (tid == 0) scnt = 0;

    // ---- camera basis ----
    const float ex = cam[0], ey = cam[1], ez = cam[2];
    float inv = 1.0f / (sqrtf(ex*ex + ey*ey + ez*ez) + 1e-8f);
    const float zx = -ex*inv, zy = -ey*inv, zz = -ez*inv;
    float xxr = zz, xyr = 0.0f, xzr = -zx;    // cross((0,1,0), z)
    inv = 1.0f / (sqrtf(xxr*xxr + xyr*xyr + xzr*xzr) + 1e-8f);
    const float xx = xxr*inv, xy = xyr*inv, xz = xzr*inv;
    float yxr = zy*xz - zz*xy;
    float yyr = zz*xx - zx*xz;
    float yzr = zx*xy - zy*xx;
    inv = 1.0f / (sqrtf(yxr*yxr + yyr*yyr + yzr*yzr) + 1e-8f);
    const float yx = yxr*inv, yy = yyr*inv, yz = yzr*inv;

    // ---- project vertices (2 per thread) ----
    for (int v = tid; v < NUM_V; v += 256) {
        float px = verts[3*v+0] - ex;
        float py = verts[3*v+1] - ey;
        float pz = verts[3*v+2] - ez;
        float vx = xx*px + xy*py + xz*pz;
        float vy = yx*px + yy*py + yz*pz;
        float vz = zx*px + zy*py + zz*pz;
        float denom = 1.0f / (vz*TAN_T + 1e-8f);
        sx[v] = vx*denom;
        sy[v] = vy*denom;
        sz[v] = vz;
    }
    __syncthreads();   // covers scnt init too

    // ---- tile rect (pixel-center corners; d affine -> corners bound it) ----
    const int j0 = (tile & 15) * 16;
    const int i0 = (tile >> 4) * 16;
    const float xL = (j0 + 0.5f )*(2.0f/IMG_H) - 1.0f;
    const float xR = (j0 + 15.5f)*(2.0f/IMG_H) - 1.0f;
    const float yT = 1.0f - (i0 + 0.5f )*(2.0f/IMG_H);
    const float yB = 1.0f - (i0 + 15.5f)*(2.0f/IMG_H);

    // ---- cull + compact this chunk's faces (one per thread, tid<64) ----
    if (tid < FPC) {
        const int f = chunk*FPC + tid;
        int i0f = faces[3*f+0], i1f = faces[3*f+1], i2f = faces[3*f+2];
        float ax = sx[i0f], ay = sy[i0f], z0 = sz[i0f];
        float bx = sx[i1f], by = sy[i1f], z1 = sz[i1f];
        float cx = sx[i2f], cy = sy[i2f], z2 = sz[i2f];
        bool keep = (z0 > 0.001f && z1 > 0.001f && z2 > 0.001f);

        float A[3], B[3], C[3];   // scaled by 100 = sqrt(1/SIGMA)
        const float px_[3] = {ax, bx, cx}, py_[3] = {ay, by, cy};
        const float qx_[3] = {bx, cx, ax}, qy_[3] = {by, cy, ay};
        #pragma unroll
        for (int k = 0; k < 3; ++k) {
            float eex = qx_[k] - px_[k];
            float eey = qy_[k] - py_[k];
            float il = 100.0f / (sqrtf(eex*eex + eey*eey) + 1e-8f);
            A[k] = eex*il;
            B[k] = eey*il;
            C[k] = (eex*py_[k] - eey*px_[k])*il;
        }

        if (keep) {
            // skip iff (min_k max_q d_k <= DCULL_S) && (max_k min_q d_k >= -DCULL_S)
            float minmx = 3.0e38f, maxmn = -3.0e38f;
            #pragma unroll
            for (int k = 0; k < 3; ++k) {
                float dTL = A[k]*yT - B[k]*xL - C[k];
                float dTR = A[k]*yT - B[k]*xR - C[k];
                float dBL = A[k]*yB - B[k]*xL - C[k];
                float dBR = A[k]*yB - B[k]*xR - C[k];
                float mx = fmaxf(fmaxf(dTL, dTR), fmaxf(dBL, dBR));
                float mn = fminf(fminf(dTL, dTR), fminf(dBL, dBR));
                minmx = fminf(minmx, mx);
                maxmn = fmaxf(maxmn, mn);
            }
            keep = !((minmx <= DCULL_S) && (maxmn >= -DCULL_S));
        }
        if (keep) {
            int s = atomicAdd(&scnt, 1);
            sfA[s] = make_float4(A[0], B[0], C[0], A[1]);
            sfB[s] = make_float4(B[1], C[1], A[2], B[2]);
            sfC[s] = C[2];
        }
    }
    __syncthreads();

    const int n = scnt;
    if (tid == 0) cnt[tile*NCHUNK + chunk] = n;
    if (n == 0) return;   // ~99% of blocks exit; slice stays unread-poisoned

    // pad to multiple of 4 with sentinels: dist=-1e30 -> contributes exactly 0
    const int npad = (4 - (n & 3)) & 3;
    if (tid < npad) {
        const int s = n + tid;
        sfA[s] = make_float4(0.0f, 0.0f, 1e30f, 0.0f);
        sfB[s] = make_float4(0.0f, -1e30f, 0.0f, 0.0f);
        sfC[s] = 0.0f;
    }
    __syncthreads();
    const int ng = (n + 3) & ~3;

    // ---- pixel for this thread: wave = 8x8 sub-tile ----
    const int w = tid >> 6, l = tid & 63;
    const int lj = (w & 1)*8 + (l & 7);
    const int li = (w >> 1)*8 + (l >> 3);
    const int j = j0 + lj, i = i0 + li;
    const float qx = (j + 0.5f)*(2.0f/IMG_H) - 1.0f;
    const float qy = 1.0f - (i + 0.5f)*(2.0f/IMG_H);

    float acc = 0.0f;
    for (int g = 0; g < ng; g += 4) {
        float dist4[4];
        #pragma unroll
        for (int u = 0; u < 4; ++u) {
            float4 w0 = sfA[g+u];
            float4 w1 = sfB[g+u];
            float  c2 = sfC[g+u];
            float d0 = fmaf(w0.x, qy, -fmaf(w0.y, qx, w0.z));
            float d1 = fmaf(w0.w, qy, -fmaf(w1.x, qx, w1.y));
            float d2 = fmaf(w1.z, qy, -fmaf(w1.w, qx, c2));
            float dmin = fminf(fminf(d0, d1), d2);
            float dmax = fmaxf(fmaxf(d0, d1), d2);
            dist4[u] = fmaxf(dmin, -dmax);   // = 100 * true dist
        }
        float gm = fmaxf(fmaxf(dist4[0], dist4[1]), fmaxf(dist4[2], dist4[3]));
        if (__any(gm > DCULL_S)) {
            #pragma unroll
            for (int u = 0; u < 4; ++u) {
                float dist = dist4[u];
                float s  = dist * fabsf(dist);        // = true dist*|dist|/SIGMA
                float e2 = __builtin_exp2f(-fabsf(s) * 1.44269504f);
                float lg = __builtin_log2f(1.0f + e2);
                float sp = fmaf(lg, 0.69314718f, fmaxf(s, 0.0f));
                acc += fmaxf(-sp, LOG_EPS);
            }
        }
    }
    // slice layout: [(tile*NCHUNK+chunk)*256 + li*16+lj] -- contiguous per block
    slices[(tile*NCHUNK + chunk)*256 + li*16 + lj] = acc;
}

// ---------------------------------------------------------------------------
// Finalize: one block per tile. Sum only chunks with cnt>0 (block-uniform
// branch; empty tiles read zero slice data -> alpha = 0 exactly), then
// squared error vs image_ref, block reduce, one atomicAdd.
// ---------------------------------------------------------------------------
__global__ __launch_bounds__(256) void finalize_kernel(
    const float* __restrict__ image_ref,
    const float* __restrict__ slices,
    const int*   __restrict__ cnt,
    const float* __restrict__ cam,
    float* __restrict__ out)
{
    __shared__ float wsum[4];
    const int tid  = threadIdx.x;
    const int tile = blockIdx.x;
    const int j0 = (tile & 15) * 16;
    const int i0 = (tile >> 4) * 16;
    const int li = tid >> 4, lj = tid & 15;        // straight map: coalesced
    const int p  = (i0 + li)*IMG_H + (j0 + lj);

    float lsum = 0.0f;
    #pragma unroll
    for (int c = 0; c < NCHUNK; ++c) {
        if (cnt[tile*NCHUNK + c] > 0)              // block-uniform branch
            lsum += slices[(tile*NCHUNK + c)*256 + tid];
    }
    float alpha = 1.0f - __expf(lsum);
    float diff  = image_ref[p] - alpha;
    float sq = diff * diff;

    #pragma unroll
    for (int off = 32; off > 0; off >>= 1) sq += __shfl_down(sq, off, 64);
    if ((tid & 63) == 0) wsum[tid >> 6] = sq;
    __syncthreads();
    if (tid == 0) {
        float ex = cam[0], ey = cam[1], ez = cam[2];
        float dist = sqrtf(ex*ex + ey*ey + ez*ez);
        float pen = fmaxf(6.0f - dist, 0.0f);
        float bs = (wsum[0] + wsum[1]) + (wsum[2] + wsum[3]);
        atomicAdd(out, bs * (1.0f + pen));
    }
}

extern "C" void kernel_launch(void* const* d_in, const int* in_sizes, int n_in,
                              void* d_out, int out_size, void* d_ws, size_t ws_size,
                              hipStream_t stream)
{
    const float* verts     = (const float*)d_in[0];  // (1,512,3)
    const int*   faces     = (const int*)  d_in[1];  // (1,1024,3)
    const float* image_ref = (const float*)d_in[2];  // (256,256)
    const float* cam       = (const float*)d_in[3];  // (3,)

    float* slices = (float*)d_ws;                        // 256*NCHUNK*256 f32 = 4 MB
    int*   cnt    = (int*)((char*)d_ws + 256*NCHUNK*256*sizeof(float)); // 16 KB
    float* out    = (float*)d_out;

    render_kernel  <<<256*NCHUNK, 256, 0, stream>>>(verts, faces, cam,
                                                    slices, cnt, out);
    finalize_kernel<<<256,        256, 0, stream>>>(image_ref, slices, cnt,
                                                    cam, out);
}